// Round 3
// baseline (1239.758 us; speedup 1.0000x reference)
//
#include <hip/hip_runtime.h>

// Conv: out = (norm * (x + segment_sum(x[sources], targets))) @ W
// N = 100000, E = 4000000, C = 64, fp32.
// Strategy: per-target linked lists (coalesced next[] writes, cheap int
// atomics on 400KB head[]), then fused chase/aggregate/scale/matmul.

constexpr int C = 64;

// --- 1. build per-target linked lists ---------------------------------------
// next[e] write is coalesced (indexed by e). atomicExch on head: 4M int
// atomics over 400KB -- L2-resident, ~15us at measured atomic rates.
__global__ __launch_bounds__(256) void link_kernel(
    const int* __restrict__ tgt, int* __restrict__ head,
    int* __restrict__ next, int E) {
  int e = blockIdx.x * 256 + threadIdx.x;
  if (e < E) {
    next[e] = atomicExch(&head[tgt[e]], e);
  }
}

// --- 2. fused chain-chase + aggregate + scale + matmul ----------------------
// One wave handles 4 nodes concurrently: 4 independent pointer-chase chains
// per wave -> 4x the memory-level parallelism on the serial next[] loads.
// x[src] row reads are 256B coalesced per wave (x is L3-resident).
__global__ __launch_bounds__(256) void fused_kernel(
    const float* __restrict__ x, const int* __restrict__ head,
    const int* __restrict__ next, const int* __restrict__ src,
    const float* __restrict__ norm, const float* __restrict__ W,
    float* __restrict__ out, int N) {
  __shared__ float w[C][C];
  int tid = threadIdx.x;
  for (int i = tid; i < C * C; i += 256) w[i >> 6][i & 63] = W[i];
  __syncthreads();

  int lane = tid & 63;
  int wave = tid >> 6;
  int gw = blockIdx.x * 4 + wave;      // global wave id
  int stride = gridDim.x * 4 * 4;      // total waves * 4 nodes each

  for (int n0 = gw * 4; n0 < N; n0 += stride) {
    int n1 = n0 + 1, n2 = n0 + 2, n3 = n0 + 3;
    bool v1 = n1 < N, v2 = n2 < N, v3 = n3 < N;

    float a0 = x[n0 * C + lane];
    float a1 = v1 ? x[n1 * C + lane] : 0.0f;
    float a2 = v2 ? x[n2 * C + lane] : 0.0f;
    float a3 = v3 ? x[n3 * C + lane] : 0.0f;

    int e0 = head[n0];
    int e1 = v1 ? head[n1] : -1;
    int e2 = v2 ? head[n2] : -1;
    int e3 = v3 ? head[n3] : -1;

    while ((e0 >= 0) | (e1 >= 0) | (e2 >= 0) | (e3 >= 0)) {
      // all four chains advance within one latency window (independent loads)
      if (e0 >= 0) { int s = src[e0]; int nx = next[e0]; a0 += x[s * C + lane]; e0 = nx; }
      if (e1 >= 0) { int s = src[e1]; int nx = next[e1]; a1 += x[s * C + lane]; e1 = nx; }
      if (e2 >= 0) { int s = src[e2]; int nx = next[e2]; a2 += x[s * C + lane]; e2 = nx; }
      if (e3 >= 0) { int s = src[e3]; int nx = next[e3]; a3 += x[s * C + lane]; e3 = nx; }
    }

    // epilogue: per-node norm scale + 64x64 matmul via shfl broadcast
    {
      float h = norm[n0] * a0;
      float o = 0.0f;
#pragma unroll
      for (int k = 0; k < C; k++) o = fmaf(__shfl(h, k, 64), w[k][lane], o);
      out[n0 * C + lane] = o;
    }
    if (v1) {
      float h = norm[n1] * a1;
      float o = 0.0f;
#pragma unroll
      for (int k = 0; k < C; k++) o = fmaf(__shfl(h, k, 64), w[k][lane], o);
      out[n1 * C + lane] = o;
    }
    if (v2) {
      float h = norm[n2] * a2;
      float o = 0.0f;
#pragma unroll
      for (int k = 0; k < C; k++) o = fmaf(__shfl(h, k, 64), w[k][lane], o);
      out[n2 * C + lane] = o;
    }
    if (v3) {
      float h = norm[n3] * a3;
      float o = 0.0f;
#pragma unroll
      for (int k = 0; k < C; k++) o = fmaf(__shfl(h, k, 64), w[k][lane], o);
      out[n3 * C + lane] = o;
    }
  }
}

extern "C" void kernel_launch(void* const* d_in, const int* in_sizes, int n_in,
                              void* d_out, int out_size, void* d_ws, size_t ws_size,
                              hipStream_t stream) {
  const float* x       = (const float*)d_in[0];
  const int*   sources = (const int*)d_in[1];
  const int*   targets = (const int*)d_in[2];
  const float* norm    = (const float*)d_in[3];
  const float* weight  = (const float*)d_in[4];
  float* out = (float*)d_out;

  int N = in_sizes[0] / C;   // 100000
  int E = in_sizes[1];       // 4000000

  // workspace: head[N] | next[E]   (16.4 MB of int)
  int* head = (int*)d_ws;
  int* next = head + N;

  // head[i] = -1  (0xFF byte pattern == -1 for int)
  hipMemsetAsync(head, 0xFF, (size_t)N * sizeof(int), stream);

  int eblocks = (E + 255) / 256;
  link_kernel<<<eblocks, 256, 0, stream>>>(targets, head, next, E);

  fused_kernel<<<2048, 256, 0, stream>>>(x, head, next, sources, norm, weight, out, N);
}